// Round 1
// baseline (369.226 us; speedup 1.0000x reference)
//
#include <hip/hip_runtime.h>
#include <hip/hip_bf16.h>

// FFB encoder, MI355X. Round 8: full-column waves, X resident in registers.
// Each wave owns ALL 128 h-rows for 32 points: acc[4] (64 VGPR) + buf[4]
// (64 VGPR). X hi/lo kept in registers as MFMA B-fragments (xh[8]/xl[8],
// 64 VGPR) -> zero LDS traffic for X in the MFMA loops. Epilogue builds
// next-level B-frags in-register via v_permlane32_swap_b32 (half-wave row
// exchange) instead of the LDS round-trip. Mid-W hi+lo single-buffered in
// 64KB LDS via async global_load_lds (DMA hidden under epilogue+high);
// high-W streamed from L2. 2 barriers/level. WG=512, 1 WG/CU, 2 waves/EU.

typedef __bf16 bf16_t;
typedef __attribute__((ext_vector_type(8))) __bf16 bf16x8;
typedef __attribute__((ext_vector_type(4))) float f32x4;
typedef __attribute__((ext_vector_type(16))) float f32x16;

#define C56R 8.9126768f               // 56 / (2*pi)
#define INV7 0.14285714285714285f

// ws layout (bytes) — frag-linear, unchanged from r4-r7
#define OFF_WMF   0        // mid W hi  [7][4mt][8kc][64lane][8bf16]
#define OFF_WMFLO 229376   // mid W lo
#define OFF_WHF   458752   // high W hi
#define OFF_EPM   688128   // [7][2hf][4mt][16r] float4 {ap0, ap1, C56R*bm, C56R*bh}

union ChunkU { bf16x8 v; unsigned int d[4]; };

__device__ __forceinline__ unsigned short bfbits(float x) {
  bf16_t b = (bf16_t)x;
  return __builtin_bit_cast(unsigned short, b);
}
__device__ __forceinline__ float bf2f(unsigned short u) {
  return __builtin_bit_cast(float, (unsigned int)u << 16);
}
__device__ __forceinline__ void pack2(float v0, float v1,
                                      unsigned int& ph, unsigned int& pl) {
  unsigned short h0 = bfbits(v0), h1 = bfbits(v1);
  ph = (unsigned int)h0 | ((unsigned int)h1 << 16);
  float l0 = v0 - bf2f(h0), l1 = v1 - bf2f(h1);
  pl = (unsigned int)bfbits(l0) | ((unsigned int)bfbits(l1) << 16);
}
// async global->LDS 16B per lane: dest = ldsbase + lane*16
__device__ __forceinline__ void stage16(const void* g, void* l) {
  __builtin_amdgcn_global_load_lds(
      (const __attribute__((address_space(1))) unsigned int*)g,
      (__attribute__((address_space(3))) unsigned int*)l, 16, 0, 0);
}

__global__ void ffb_prep(const float* __restrict__ ffnA, const float* __restrict__ sigma,
                         const float* __restrict__ Wm, const float* __restrict__ bm,
                         const float* __restrict__ Wh, const float* __restrict__ bh,
                         unsigned char* __restrict__ ws) {
  int i = blockIdx.x * 256 + threadIdx.x;  // 448*256 = 114688 exactly
  bf16_t* wmf = (bf16_t*)(ws + OFF_WMF);
  bf16_t* wml = (bf16_t*)(ws + OFF_WMFLO);
  bf16_t* whf = (bf16_t*)(ws + OFF_WHF);
  {
    // fragment reorder: [it][mt][kc][lane][j]
    int j    = i & 7;
    int lane = (i >> 3) & 63;
    int kc   = (i >> 9) & 7;
    int mt   = (i >> 12) & 3;
    int it   = i >> 14;                       // 0..6
    int ho   = (mt << 5) + (lane & 31);
    int hin  = (kc << 4) + ((lane >> 5) << 3) + j;
    int src  = (it << 14) + (ho << 7) + hin;
    float w  = Wm[src];
    bf16_t h = (bf16_t)w;
    wmf[i] = h;
    wml[i] = (bf16_t)(w - (float)h);
    whf[i] = (bf16_t)Wh[src];
  }
  if (i < 896) {
    int r  = i & 15;
    int mt = (i >> 4) & 3;
    int hf = (i >> 6) & 1;
    int it = i >> 7;                          // 0..6
    int h  = (mt << 5) + (r & 3) + ((r >> 2) << 3) + (hf << 2);
    float sg = sigma[it];
    f32x4 e;
    e.x = ffnA[it * 256 + h] * sg;
    e.y = ffnA[it * 256 + 128 + h] * sg;
    e.z = C56R * bm[it * 128 + h];
    e.w = C56R * bh[it * 128 + h];
    ((f32x4*)(ws + OFF_EPM))[i] = e;
  }
}

__launch_bounds__(512, 2)
__global__ void ffb_main(const float* __restrict__ pos,
                         const float* __restrict__ gfeat,
                         const float* __restrict__ W0,
                         const float* __restrict__ b0,
                         const unsigned char* __restrict__ ws,
                         float* __restrict__ out) {
  // LDS: mid W for current level: [hl:2][mt:4][kc:8][64lane][16B] = 64KB
  __shared__ __align__(16) unsigned char sW[65536];

  const int tid  = threadIdx.x;
  const int L    = tid & 63;
  const int wave = tid >> 6;        // 0..7, each owns 32 points
  const int p    = L & 31;
  const int hf   = L >> 5;
  const int n    = (blockIdx.x << 8) + (wave << 5) + p;

  const bf16_t* __restrict__ WHF = (const bf16_t*)(ws + OFF_WHF);
  const f32x4*  __restrict__ EPM = (const f32x4*)(ws + OFF_EPM);
  const float*  __restrict__ EPW = (const float*)(ws + OFF_EPM);

  // issue level-0 mid-W stage: waves 0-3 hi (mt=wave), waves 4-7 lo
  {
    const unsigned char* srcb = ws + (wave < 4 ? OFF_WMF : OFF_WMFLO)
                              + ((wave & 3) << 13) + (L << 4);
    unsigned char* dstb = sW + ((wave >> 2) << 15) + ((wave & 3) << 13);
    #pragma unroll
    for (int c = 0; c < 8; ++c)
      stage16(srcb + (c << 10), dstb + (c << 10));
  }

  const float p0 = pos[n * 3 + 0], p1 = pos[n * 3 + 1], p2 = pos[n * 3 + 2];
  if (hf == 0) {
    out[(size_t)n * 131 + 0] = (p0 + 1.f) * 0.5f;
    out[(size_t)n * 131 + 1] = (p1 + 1.f) * 0.5f;
    out[(size_t)n * 131 + 2] = (p2 + 1.f) * 0.5f;
  }

  // ---- layer 0: build ALL X B-fragments in registers (covers DMA latency)
  bf16x8 xh[8], xl[8];
  #pragma unroll
  for (int kc = 0; kc < 8; ++kc) {
    ChunkU chi, clo;
    #pragma unroll
    for (int jp = 0; jp < 4; ++jp) {
      const int h0 = (kc << 4) + (hf << 3) + 2 * jp;
      float d0 = __builtin_fmaf(p2, W0[h0*3+2], __builtin_fmaf(p1, W0[h0*3+1], p0 * W0[h0*3+0]));
      float d1 = __builtin_fmaf(p2, W0[h0*3+5], __builtin_fmaf(p1, W0[h0*3+4], p0 * W0[h0*3+3]));
      float v0 = __builtin_amdgcn_sinf(C56R * (d0 + b0[h0]));
      float v1 = __builtin_amdgcn_sinf(C56R * (d1 + b0[h0 + 1]));
      pack2(v0, v1, chi.d[jp], clo.d[jp]);
    }
    xh[kc] = chi.v;
    xl[kc] = clo.v;
  }

  f32x16 buf[4];
  #pragma unroll
  for (int mt = 0; mt < 4; ++mt)
    #pragma unroll
    for (int r = 0; r < 16; ++r) buf[mt][r] = 0.f;

  __syncthreads();   // level-0 mid-W staged (vmcnt drained per wave)

  #pragma unroll 1
  for (int l = 0; l < 7; ++l) {
    // ---- mid pass: acc[mt] = WmH*Xh + WmL*Xh + WmH*Xl, W frags from LDS
    f32x16 acc[4];
    #pragma unroll
    for (int mt = 0; mt < 4; ++mt)
      #pragma unroll
      for (int r = 0; r < 16; ++r) acc[mt][r] = 0.f;

    #pragma unroll
    for (int kc = 0; kc < 8; ++kc) {
      #pragma unroll
      for (int mt = 0; mt < 4; ++mt) {
        const bf16x8 fh = *(const bf16x8*)(sW + (mt << 13) + (kc << 10) + (L << 4));
        const bf16x8 fl = *(const bf16x8*)(sW + 32768 + (mt << 13) + (kc << 10) + (L << 4));
        acc[mt] = __builtin_amdgcn_mfma_f32_32x32x16_bf16(fh, xh[kc], acc[mt], 0, 0, 0);
        acc[mt] = __builtin_amdgcn_mfma_f32_32x32x16_bf16(fl, xh[kc], acc[mt], 0, 0, 0);
        acc[mt] = __builtin_amdgcn_mfma_f32_32x32x16_bf16(fh, xl[kc], acc[mt], 0, 0, 0);
      }
    }
    __syncthreads();   // B1: all waves done reading sW(l)

    // stage next level's mid W (async DMA, overlaps epilogue + high pass)
    if (l < 6) {
      const unsigned char* srcb = ws + (wave < 4 ? OFF_WMF : OFF_WMFLO)
                                + ((l + 1) << 15) + ((wave & 3) << 13) + (L << 4);
      unsigned char* dstb = sW + ((wave >> 2) << 15) + ((wave & 3) << 13);
      #pragma unroll
      for (int c = 0; c < 8; ++c)
        stage16(srcb + (c << 10), dstb + (c << 10));
    }

    // ---- epilogue: x(l+1) = sin(grid) + sin(56*mid+bm); build B-frags
    // in-register. acc C-layout puts rows 0-3 (mod 8) in lanes<32 and 4-7
    // (mod 8) in lanes>=32; permlane32_swap exchanges exactly those halves.
    const float g0 = gfeat[n * 17 + 3 + 2 * l];
    const float g1 = gfeat[n * 17 + 4 + 2 * l];
    #pragma unroll
    for (int mt = 0; mt < 4; ++mt) {
      const int eb = (((l << 1) + hf) << 2) + mt;
      float v[16];
      #pragma unroll
      for (int r = 0; r < 16; ++r) {
        const f32x4 e = EPM[eb * 16 + r];
        const float sg = __builtin_amdgcn_sinf(__builtin_amdgcn_fractf(__builtin_fmaf(g1, e.y, g0 * e.x)));
        const float sm = __builtin_amdgcn_sinf(__builtin_fmaf(acc[mt][r], C56R, e.z));
        v[r] = sg + sm;
      }
      #pragma unroll
      for (int bh = 0; bh < 2; ++bh) {
        unsigned int Ah, Al, Bh, Bl, Ch, Cl, Dh, Dl;
        pack2(v[8*bh + 0], v[8*bh + 1], Ah, Al);
        pack2(v[8*bh + 2], v[8*bh + 3], Bh, Bl);
        pack2(v[8*bh + 4], v[8*bh + 5], Ch, Cl);
        pack2(v[8*bh + 6], v[8*bh + 7], Dh, Dl);
        // swap vdst upper half-wave with vsrc lower half-wave
        asm("v_permlane32_swap_b32 %0, %1" : "+v"(Ah), "+v"(Ch));
        asm("v_permlane32_swap_b32 %0, %1" : "+v"(Bh), "+v"(Dh));
        asm("v_permlane32_swap_b32 %0, %1" : "+v"(Al), "+v"(Cl));
        asm("v_permlane32_swap_b32 %0, %1" : "+v"(Bl), "+v"(Dl));
        ChunkU uh, ul;
        uh.d[0] = Ah; uh.d[1] = Bh; uh.d[2] = Ch; uh.d[3] = Dh;
        ul.d[0] = Al; ul.d[1] = Bl; ul.d[2] = Cl; ul.d[3] = Dl;
        xh[2*mt + bh] = uh.v;
        xl[2*mt + bh] = ul.v;
      }
    }

    // ---- high pass: buf += sin(56*(WhH*Xh) + bh), W streamed from L2
    f32x16 hac[4];
    #pragma unroll
    for (int mt = 0; mt < 4; ++mt)
      #pragma unroll
      for (int r = 0; r < 16; ++r) hac[mt][r] = 0.f;

    const bf16_t* whb = WHF + (l << 14) + (L << 3);
    #pragma unroll
    for (int kc = 0; kc < 8; ++kc) {
      #pragma unroll
      for (int mt = 0; mt < 4; ++mt) {
        const bf16x8 f = *(const bf16x8*)(whb + (mt << 12) + (kc << 9));
        hac[mt] = __builtin_amdgcn_mfma_f32_32x32x16_bf16(f, xh[kc], hac[mt], 0, 0, 0);
      }
    }
    #pragma unroll
    for (int mt = 0; mt < 4; ++mt) {
      const int eb = (((l << 1) + hf) << 2) + mt;
      #pragma unroll
      for (int r = 0; r < 16; ++r) {
        const float cbh = EPW[(eb * 16 + r) * 4 + 3];
        buf[mt][r] += __builtin_amdgcn_sinf(__builtin_fmaf(hac[mt][r], C56R, cbh));
      }
    }
    __syncthreads();   // B2: next-level mid-W DMA drained on every wave
  }

  // ---- final store: all 128 rows for this wave's 32 points
  float* op = out + (size_t)n * 131 + 3;
  #pragma unroll
  for (int mt = 0; mt < 4; ++mt) {
    #pragma unroll
    for (int r = 0; r < 16; ++r) {
      const int h = (mt << 5) + (r & 3) + ((r >> 2) << 3) + (hf << 2);
      op[h] = buf[mt][r] * INV7;
    }
  }
}

extern "C" void kernel_launch(void* const* d_in, const int* in_sizes, int n_in,
                              void* d_out, int out_size, void* d_ws, size_t ws_size,
                              hipStream_t stream) {
  (void)in_sizes; (void)n_in; (void)out_size; (void)ws_size;
  const float* pos   = (const float*)d_in[0];
  const float* gfeat = (const float*)d_in[1];
  const float* ffnA  = (const float*)d_in[2];
  const float* sigma = (const float*)d_in[3];
  const float* W0    = (const float*)d_in[4];
  const float* b0    = (const float*)d_in[5];
  const float* Wm    = (const float*)d_in[6];
  const float* bm    = (const float*)d_in[7];
  const float* Wh    = (const float*)d_in[8];
  const float* bh    = (const float*)d_in[9];
  float* out = (float*)d_out;
  unsigned char* ws = (unsigned char*)d_ws;

  hipLaunchKernelGGL(ffb_prep, dim3(448), dim3(256), 0, stream,
                     ffnA, sigma, Wm, bm, Wh, bh, ws);
  hipLaunchKernelGGL(ffb_main, dim3(512), dim3(512), 0, stream,
                     pos, gfeat, W0, b0, ws, out);
}

// Round 2
// 347.908 us; speedup vs baseline: 1.0613x; 1.0613x over previous
//
#include <hip/hip_runtime.h>
#include <hip/hip_bf16.h>

// FFB encoder, MI355X. Round 9: max-TLP variant of the r7 quad structure.
// One quad per WG (4 waves, 32 points, each wave owns one 32-row mt tile:
// acc 16 + buf 16 regs). X hi/lo in 16KB LDS (B-frag layout, r7-identical).
// ALL W fragments (mid-hi, mid-lo, high) stream from L2 with register
// prefetch -- no LDS W staging, no DMA, no vmcnt-coupled barrier. LDS
// 16KB + ~60 VGPR -> target 8 WG/CU (32 waves), hiding the MFMA<->VALU
// antiphase and barrier drains with TLP instead of intra-wave pipelining.
// W working set (688KB) is L2-resident; extra L2 reads ~2.75GB ~= 80us
// aggregate, overlapped. Numerics bit-identical to r7 (absmax 0.0059).

typedef __bf16 bf16_t;
typedef __attribute__((ext_vector_type(8))) __bf16 bf16x8;
typedef __attribute__((ext_vector_type(4))) float f32x4;
typedef __attribute__((ext_vector_type(16))) float f32x16;

#define C56R 8.9126768f               // 56 / (2*pi)
#define INV7 0.14285714285714285f

// ws layout (bytes) — frag-linear, unchanged from r4-r8
#define OFF_WMF   0        // mid W hi  [7][4mt][8kc][64lane][8bf16]
#define OFF_WMFLO 229376   // mid W lo
#define OFF_WHF   458752   // high W hi
#define OFF_EPM   688128   // [7][2hf][4mt][16r] float4 {ap0, ap1, C56R*bm, C56R*bh}

union ChunkU { bf16x8 v; unsigned int d[4]; };

__device__ __forceinline__ unsigned short bfbits(float x) {
  bf16_t b = (bf16_t)x;
  return __builtin_bit_cast(unsigned short, b);
}
__device__ __forceinline__ float bf2f(unsigned short u) {
  return __builtin_bit_cast(float, (unsigned int)u << 16);
}
__device__ __forceinline__ void pack2(float v0, float v1,
                                      unsigned int& ph, unsigned int& pl) {
  unsigned short h0 = bfbits(v0), h1 = bfbits(v1);
  ph = (unsigned int)h0 | ((unsigned int)h1 << 16);
  float l0 = v0 - bf2f(h0), l1 = v1 - bf2f(h1);
  pl = (unsigned int)bfbits(l0) | ((unsigned int)bfbits(l1) << 16);
}

__global__ void ffb_prep(const float* __restrict__ ffnA, const float* __restrict__ sigma,
                         const float* __restrict__ Wm, const float* __restrict__ bm,
                         const float* __restrict__ Wh, const float* __restrict__ bh,
                         unsigned char* __restrict__ ws) {
  int i = blockIdx.x * 256 + threadIdx.x;  // 448*256 = 114688 exactly
  bf16_t* wmf = (bf16_t*)(ws + OFF_WMF);
  bf16_t* wml = (bf16_t*)(ws + OFF_WMFLO);
  bf16_t* whf = (bf16_t*)(ws + OFF_WHF);
  {
    // fragment reorder: [it][mt][kc][lane][j]
    int j    = i & 7;
    int lane = (i >> 3) & 63;
    int kc   = (i >> 9) & 7;
    int mt   = (i >> 12) & 3;
    int it   = i >> 14;                       // 0..6
    int ho   = (mt << 5) + (lane & 31);
    int hin  = (kc << 4) + ((lane >> 5) << 3) + j;
    int src  = (it << 14) + (ho << 7) + hin;
    float w  = Wm[src];
    bf16_t h = (bf16_t)w;
    wmf[i] = h;
    wml[i] = (bf16_t)(w - (float)h);
    whf[i] = (bf16_t)Wh[src];
  }
  if (i < 896) {
    int r  = i & 15;
    int mt = (i >> 4) & 3;
    int hf = (i >> 6) & 1;
    int it = i >> 7;                          // 0..6
    int h  = (mt << 5) + (r & 3) + ((r >> 2) << 3) + (hf << 2);
    float sg = sigma[it];
    f32x4 e;
    e.x = ffnA[it * 256 + h] * sg;
    e.y = ffnA[it * 256 + 128 + h] * sg;
    e.z = C56R * bm[it * 128 + h];
    e.w = C56R * bh[it * 128 + h];
    ((f32x4*)(ws + OFF_EPM))[i] = e;
  }
}

__launch_bounds__(256, 8)
__global__ void ffb_main(const float* __restrict__ pos,
                         const float* __restrict__ gfeat,
                         const float* __restrict__ W0,
                         const float* __restrict__ b0,
                         const unsigned char* __restrict__ ws,
                         float* __restrict__ out) {
  // LDS: X for this quad only: hi [kc:8][64lane][16B] = 8KB, lo at +8KB
  __shared__ __align__(16) unsigned char sX[16384];

  const int tid  = threadIdx.x;
  const int L    = tid & 63;
  const int sub  = tid >> 6;        // wave 0..3 = mt tile owned
  const int p    = L & 31;
  const int hf   = L >> 5;
  const int n    = (blockIdx.x << 5) + p;

  const bf16_t* __restrict__ WMH = (const bf16_t*)(ws + OFF_WMF);
  const bf16_t* __restrict__ WML = (const bf16_t*)(ws + OFF_WMFLO);
  const bf16_t* __restrict__ WHF = (const bf16_t*)(ws + OFF_WHF);
  const f32x4*  __restrict__ EPM = (const f32x4*)(ws + OFF_EPM);
  const float*  __restrict__ EPW = (const float*)(ws + OFF_EPM);

  const float p0 = pos[n * 3 + 0], p1 = pos[n * 3 + 1], p2 = pos[n * 3 + 2];
  if (sub == 0 && hf == 0) {
    out[(size_t)n * 131 + 0] = (p0 + 1.f) * 0.5f;
    out[(size_t)n * 131 + 1] = (p1 + 1.f) * 0.5f;
    out[(size_t)n * 131 + 2] = (p2 + 1.f) * 0.5f;
  }

  // ---- layer 0: each wave fills its 2 X chunks (B-frag layout) in LDS.
  #pragma unroll
  for (int cc = 0; cc < 2; ++cc) {
    const int c = (sub << 1) + cc;
    ChunkU chi, clo;
    #pragma unroll
    for (int jp = 0; jp < 4; ++jp) {
      int h0 = (c << 4) + (hf << 3) + 2 * jp;
      float d0 = __builtin_fmaf(p2, W0[h0*3+2], __builtin_fmaf(p1, W0[h0*3+1], p0 * W0[h0*3+0]));
      float d1 = __builtin_fmaf(p2, W0[h0*3+5], __builtin_fmaf(p1, W0[h0*3+4], p0 * W0[h0*3+3]));
      float v0 = __builtin_amdgcn_sinf(C56R * (d0 + b0[h0]));
      float v1 = __builtin_amdgcn_sinf(C56R * (d1 + b0[h0 + 1]));
      pack2(v0, v1, chi.d[jp], clo.d[jp]);
    }
    *(bf16x8*)(sX + (c << 10) + (L << 4))        = chi.v;
    *(bf16x8*)(sX + 8192 + (c << 10) + (L << 4)) = clo.v;
  }
  __syncthreads();   // X0 visible

  f32x16 buf;
  #pragma unroll
  for (int r = 0; r < 16; ++r) buf[r] = 0.f;

  for (int it = 0; it < 8; ++it) {
    // ---- high pass: level it-1, W frags from L2 (prefetch-1), X-hi from LDS
    if (it > 0) {
      f32x16 acc;
      #pragma unroll
      for (int r = 0; r < 16; ++r) acc[r] = 0.f;
      const bf16_t* wb = WHF + ((it - 1) << 14) + (sub << 12) + (L << 3);
      bf16x8 fnext = *(const bf16x8*)(wb);
      #pragma unroll
      for (int kc = 0; kc < 8; ++kc) {
        bf16x8 f = fnext;
        if (kc < 7) fnext = *(const bf16x8*)(wb + ((kc + 1) << 9));
        bf16x8 xhc = *(const bf16x8*)(sX + (kc << 10) + (L << 4));
        acc = __builtin_amdgcn_mfma_f32_32x32x16_bf16(f, xhc, acc, 0, 0, 0);
      }
      const int eb = ((((it - 1) << 1) + hf) << 2) + sub;
      #pragma unroll
      for (int r = 0; r < 16; ++r) {
        float cbh = EPW[(eb * 16 + r) * 4 + 3];
        buf[r] += __builtin_amdgcn_sinf(__builtin_fmaf(acc[r], C56R, cbh));
      }
    }

    // ---- mid pass: level it, all W frags streamed from L2 (prefetch-1)
    if (it < 7) {
      f32x16 acc;
      #pragma unroll
      for (int r = 0; r < 16; ++r) acc[r] = 0.f;
      const bf16_t* wh = WMH + (it << 14) + (sub << 12) + (L << 3);
      const bf16_t* wl = WML + (it << 14) + (sub << 12) + (L << 3);
      bf16x8 fhnext = *(const bf16x8*)(wh);
      bf16x8 flnext = *(const bf16x8*)(wl);
      #pragma unroll
      for (int kc = 0; kc < 8; ++kc) {
        bf16x8 fh = fhnext;
        bf16x8 fl = flnext;
        if (kc < 7) {
          fhnext = *(const bf16x8*)(wh + ((kc + 1) << 9));
          flnext = *(const bf16x8*)(wl + ((kc + 1) << 9));
        }
        bf16x8 xhc = *(const bf16x8*)(sX + (kc << 10) + (L << 4));
        bf16x8 xlc = *(const bf16x8*)(sX + 8192 + (kc << 10) + (L << 4));
        acc = __builtin_amdgcn_mfma_f32_32x32x16_bf16(fh, xhc, acc, 0, 0, 0);
        acc = __builtin_amdgcn_mfma_f32_32x32x16_bf16(fl, xhc, acc, 0, 0, 0);
        acc = __builtin_amdgcn_mfma_f32_32x32x16_bf16(fh, xlc, acc, 0, 0, 0);
      }

      __syncthreads();   // B1: all reads of X(it) complete

      // epilogue: x(it+1) = sin(grid) + sin(56*mid+b); write to B-layout LDS
      const float g0 = gfeat[n * 17 + 3 + 2 * it];
      const float g1 = gfeat[n * 17 + 4 + 2 * it];
      const int eb = (((it << 1) + hf) << 2) + sub;
      #pragma unroll
      for (int rp = 0; rp < 8; ++rp) {
        const int r = 2 * rp;
        f32x4 e0 = EPM[eb * 16 + r];
        f32x4 e1 = EPM[eb * 16 + r + 1];
        float sg0 = __builtin_amdgcn_sinf(__builtin_amdgcn_fractf(__builtin_fmaf(g1, e0.y, g0 * e0.x)));
        float sg1 = __builtin_amdgcn_sinf(__builtin_amdgcn_fractf(__builtin_fmaf(g1, e1.y, g0 * e1.x)));
        float sm0 = __builtin_amdgcn_sinf(__builtin_fmaf(acc[r],     C56R, e0.z));
        float sm1 = __builtin_amdgcn_sinf(__builtin_fmaf(acc[r + 1], C56R, e1.z));
        unsigned int phv, plv;
        pack2(sg0 + sm0, sg1 + sm1, phv, plv);
        const int h   = (sub << 5) + (r & 3) + ((r >> 2) << 3) + (hf << 2);
        const int off = ((h >> 4) << 10) + ((p + (((h >> 3) & 1) << 5)) << 4) + ((h & 7) << 1);
        *(unsigned int*)(sX + off)        = phv;
        *(unsigned int*)(sX + 8192 + off) = plv;
      }
      __syncthreads();   // B2: X(it+1) visible
    }
  }

  // ---- final store: this wave's mt=sub rows for its 32 points.
  float* op = out + (size_t)n * 131 + 3;
  #pragma unroll
  for (int r = 0; r < 16; ++r) {
    const int h = (sub << 5) + (r & 3) + ((r >> 2) << 3) + (hf << 2);
    op[h] = buf[r] * INV7;
  }
}

extern "C" void kernel_launch(void* const* d_in, const int* in_sizes, int n_in,
                              void* d_out, int out_size, void* d_ws, size_t ws_size,
                              hipStream_t stream) {
  (void)in_sizes; (void)n_in; (void)out_size; (void)ws_size;
  const float* pos   = (const float*)d_in[0];
  const float* gfeat = (const float*)d_in[1];
  const float* ffnA  = (const float*)d_in[2];
  const float* sigma = (const float*)d_in[3];
  const float* W0    = (const float*)d_in[4];
  const float* b0    = (const float*)d_in[5];
  const float* Wm    = (const float*)d_in[6];
  const float* bm    = (const float*)d_in[7];
  const float* Wh    = (const float*)d_in[8];
  const float* bh    = (const float*)d_in[9];
  float* out = (float*)d_out;
  unsigned char* ws = (unsigned char*)d_ws;

  hipLaunchKernelGGL(ffb_prep, dim3(448), dim3(256), 0, stream,
                     ffnA, sigma, Wm, bm, Wh, bh, ws);
  hipLaunchKernelGGL(ffb_main, dim3(4096), dim3(256), 0, stream,
                     pos, gfeat, W0, b0, ws, out);
}

// Round 3
// 282.478 us; speedup vs baseline: 1.3071x; 1.2316x over previous
//
#include <hip/hip_runtime.h>
#include <hip/hip_bf16.h>

// FFB encoder, MI355X. Round 10: r9 structure with the spill fixed.
// r9 forced 8 waves/EU -> 64-VGPR cap -> massive scratch spill (WRITE_SIZE
// 307MB vs 71MB output, FETCH +67MB). Body genuinely needs ~80 VGPR
// (acc 16 + buf 16 + dual W prefetch 8 + X frags 8 + temps). Fix:
// __launch_bounds__(256, 6) -> 85-VGPR budget, 24 waves/CU (75% occ),
// LDS 16KB/WG (6 WG/CU = 96KB, not binding). Otherwise byte-identical:
// one quad per WG, X hi/lo in LDS (B-frag layout), all W fragments
// streamed from L2 with prefetch-1, 2 barriers/level.

typedef __bf16 bf16_t;
typedef __attribute__((ext_vector_type(8))) __bf16 bf16x8;
typedef __attribute__((ext_vector_type(4))) float f32x4;
typedef __attribute__((ext_vector_type(16))) float f32x16;

#define C56R 8.9126768f               // 56 / (2*pi)
#define INV7 0.14285714285714285f

// ws layout (bytes) — frag-linear, unchanged from r4-r9
#define OFF_WMF   0        // mid W hi  [7][4mt][8kc][64lane][8bf16]
#define OFF_WMFLO 229376   // mid W lo
#define OFF_WHF   458752   // high W hi
#define OFF_EPM   688128   // [7][2hf][4mt][16r] float4 {ap0, ap1, C56R*bm, C56R*bh}

union ChunkU { bf16x8 v; unsigned int d[4]; };

__device__ __forceinline__ unsigned short bfbits(float x) {
  bf16_t b = (bf16_t)x;
  return __builtin_bit_cast(unsigned short, b);
}
__device__ __forceinline__ float bf2f(unsigned short u) {
  return __builtin_bit_cast(float, (unsigned int)u << 16);
}
__device__ __forceinline__ void pack2(float v0, float v1,
                                      unsigned int& ph, unsigned int& pl) {
  unsigned short h0 = bfbits(v0), h1 = bfbits(v1);
  ph = (unsigned int)h0 | ((unsigned int)h1 << 16);
  float l0 = v0 - bf2f(h0), l1 = v1 - bf2f(h1);
  pl = (unsigned int)bfbits(l0) | ((unsigned int)bfbits(l1) << 16);
}

__global__ void ffb_prep(const float* __restrict__ ffnA, const float* __restrict__ sigma,
                         const float* __restrict__ Wm, const float* __restrict__ bm,
                         const float* __restrict__ Wh, const float* __restrict__ bh,
                         unsigned char* __restrict__ ws) {
  int i = blockIdx.x * 256 + threadIdx.x;  // 448*256 = 114688 exactly
  bf16_t* wmf = (bf16_t*)(ws + OFF_WMF);
  bf16_t* wml = (bf16_t*)(ws + OFF_WMFLO);
  bf16_t* whf = (bf16_t*)(ws + OFF_WHF);
  {
    // fragment reorder: [it][mt][kc][lane][j]
    int j    = i & 7;
    int lane = (i >> 3) & 63;
    int kc   = (i >> 9) & 7;
    int mt   = (i >> 12) & 3;
    int it   = i >> 14;                       // 0..6
    int ho   = (mt << 5) + (lane & 31);
    int hin  = (kc << 4) + ((lane >> 5) << 3) + j;
    int src  = (it << 14) + (ho << 7) + hin;
    float w  = Wm[src];
    bf16_t h = (bf16_t)w;
    wmf[i] = h;
    wml[i] = (bf16_t)(w - (float)h);
    whf[i] = (bf16_t)Wh[src];
  }
  if (i < 896) {
    int r  = i & 15;
    int mt = (i >> 4) & 3;
    int hf = (i >> 6) & 1;
    int it = i >> 7;                          // 0..6
    int h  = (mt << 5) + (r & 3) + ((r >> 2) << 3) + (hf << 2);
    float sg = sigma[it];
    f32x4 e;
    e.x = ffnA[it * 256 + h] * sg;
    e.y = ffnA[it * 256 + 128 + h] * sg;
    e.z = C56R * bm[it * 128 + h];
    e.w = C56R * bh[it * 128 + h];
    ((f32x4*)(ws + OFF_EPM))[i] = e;
  }
}

__launch_bounds__(256, 6)
__global__ void ffb_main(const float* __restrict__ pos,
                         const float* __restrict__ gfeat,
                         const float* __restrict__ W0,
                         const float* __restrict__ b0,
                         const unsigned char* __restrict__ ws,
                         float* __restrict__ out) {
  // LDS: X for this quad only: hi [kc:8][64lane][16B] = 8KB, lo at +8KB
  __shared__ __align__(16) unsigned char sX[16384];

  const int tid  = threadIdx.x;
  const int L    = tid & 63;
  const int sub  = tid >> 6;        // wave 0..3 = mt tile owned
  const int p    = L & 31;
  const int hf   = L >> 5;
  const int n    = (blockIdx.x << 5) + p;

  const bf16_t* __restrict__ WMH = (const bf16_t*)(ws + OFF_WMF);
  const bf16_t* __restrict__ WML = (const bf16_t*)(ws + OFF_WMFLO);
  const bf16_t* __restrict__ WHF = (const bf16_t*)(ws + OFF_WHF);
  const f32x4*  __restrict__ EPM = (const f32x4*)(ws + OFF_EPM);
  const float*  __restrict__ EPW = (const float*)(ws + OFF_EPM);

  const float p0 = pos[n * 3 + 0], p1 = pos[n * 3 + 1], p2 = pos[n * 3 + 2];
  if (sub == 0 && hf == 0) {
    out[(size_t)n * 131 + 0] = (p0 + 1.f) * 0.5f;
    out[(size_t)n * 131 + 1] = (p1 + 1.f) * 0.5f;
    out[(size_t)n * 131 + 2] = (p2 + 1.f) * 0.5f;
  }

  // ---- layer 0: each wave fills its 2 X chunks (B-frag layout) in LDS.
  #pragma unroll
  for (int cc = 0; cc < 2; ++cc) {
    const int c = (sub << 1) + cc;
    ChunkU chi, clo;
    #pragma unroll
    for (int jp = 0; jp < 4; ++jp) {
      int h0 = (c << 4) + (hf << 3) + 2 * jp;
      float d0 = __builtin_fmaf(p2, W0[h0*3+2], __builtin_fmaf(p1, W0[h0*3+1], p0 * W0[h0*3+0]));
      float d1 = __builtin_fmaf(p2, W0[h0*3+5], __builtin_fmaf(p1, W0[h0*3+4], p0 * W0[h0*3+3]));
      float v0 = __builtin_amdgcn_sinf(C56R * (d0 + b0[h0]));
      float v1 = __builtin_amdgcn_sinf(C56R * (d1 + b0[h0 + 1]));
      pack2(v0, v1, chi.d[jp], clo.d[jp]);
    }
    *(bf16x8*)(sX + (c << 10) + (L << 4))        = chi.v;
    *(bf16x8*)(sX + 8192 + (c << 10) + (L << 4)) = clo.v;
  }
  __syncthreads();   // X0 visible

  f32x16 buf;
  #pragma unroll
  for (int r = 0; r < 16; ++r) buf[r] = 0.f;

  for (int it = 0; it < 8; ++it) {
    // ---- high pass: level it-1, W frags from L2 (prefetch-1), X-hi from LDS
    if (it > 0) {
      f32x16 acc;
      #pragma unroll
      for (int r = 0; r < 16; ++r) acc[r] = 0.f;
      const bf16_t* wb = WHF + ((it - 1) << 14) + (sub << 12) + (L << 3);
      bf16x8 fnext = *(const bf16x8*)(wb);
      #pragma unroll
      for (int kc = 0; kc < 8; ++kc) {
        bf16x8 f = fnext;
        if (kc < 7) fnext = *(const bf16x8*)(wb + ((kc + 1) << 9));
        bf16x8 xhc = *(const bf16x8*)(sX + (kc << 10) + (L << 4));
        acc = __builtin_amdgcn_mfma_f32_32x32x16_bf16(f, xhc, acc, 0, 0, 0);
      }
      const int eb = ((((it - 1) << 1) + hf) << 2) + sub;
      #pragma unroll
      for (int r = 0; r < 16; ++r) {
        float cbh = EPW[(eb * 16 + r) * 4 + 3];
        buf[r] += __builtin_amdgcn_sinf(__builtin_fmaf(acc[r], C56R, cbh));
      }
    }

    // ---- mid pass: level it, all W frags streamed from L2 (prefetch-1)
    if (it < 7) {
      f32x16 acc;
      #pragma unroll
      for (int r = 0; r < 16; ++r) acc[r] = 0.f;
      const bf16_t* wh = WMH + (it << 14) + (sub << 12) + (L << 3);
      const bf16_t* wl = WML + (it << 14) + (sub << 12) + (L << 3);
      bf16x8 fhnext = *(const bf16x8*)(wh);
      bf16x8 flnext = *(const bf16x8*)(wl);
      #pragma unroll
      for (int kc = 0; kc < 8; ++kc) {
        bf16x8 fh = fhnext;
        bf16x8 fl = flnext;
        if (kc < 7) {
          fhnext = *(const bf16x8*)(wh + ((kc + 1) << 9));
          flnext = *(const bf16x8*)(wl + ((kc + 1) << 9));
        }
        bf16x8 xhc = *(const bf16x8*)(sX + (kc << 10) + (L << 4));
        bf16x8 xlc = *(const bf16x8*)(sX + 8192 + (kc << 10) + (L << 4));
        acc = __builtin_amdgcn_mfma_f32_32x32x16_bf16(fh, xhc, acc, 0, 0, 0);
        acc = __builtin_amdgcn_mfma_f32_32x32x16_bf16(fl, xhc, acc, 0, 0, 0);
        acc = __builtin_amdgcn_mfma_f32_32x32x16_bf16(fh, xlc, acc, 0, 0, 0);
      }

      __syncthreads();   // B1: all reads of X(it) complete

      // epilogue: x(it+1) = sin(grid) + sin(56*mid+b); write to B-layout LDS
      const float g0 = gfeat[n * 17 + 3 + 2 * it];
      const float g1 = gfeat[n * 17 + 4 + 2 * it];
      const int eb = (((it << 1) + hf) << 2) + sub;
      #pragma unroll
      for (int rp = 0; rp < 8; ++rp) {
        const int r = 2 * rp;
        f32x4 e0 = EPM[eb * 16 + r];
        f32x4 e1 = EPM[eb * 16 + r + 1];
        float sg0 = __builtin_amdgcn_sinf(__builtin_amdgcn_fractf(__builtin_fmaf(g1, e0.y, g0 * e0.x)));
        float sg1 = __builtin_amdgcn_sinf(__builtin_amdgcn_fractf(__builtin_fmaf(g1, e1.y, g0 * e1.x)));
        float sm0 = __builtin_amdgcn_sinf(__builtin_fmaf(acc[r],     C56R, e0.z));
        float sm1 = __builtin_amdgcn_sinf(__builtin_fmaf(acc[r + 1], C56R, e1.z));
        unsigned int phv, plv;
        pack2(sg0 + sm0, sg1 + sm1, phv, plv);
        const int h   = (sub << 5) + (r & 3) + ((r >> 2) << 3) + (hf << 2);
        const int off = ((h >> 4) << 10) + ((p + (((h >> 3) & 1) << 5)) << 4) + ((h & 7) << 1);
        *(unsigned int*)(sX + off)        = phv;
        *(unsigned int*)(sX + 8192 + off) = plv;
      }
      __syncthreads();   // B2: X(it+1) visible
    }
  }

  // ---- final store: this wave's mt=sub rows for its 32 points.
  float* op = out + (size_t)n * 131 + 3;
  #pragma unroll
  for (int r = 0; r < 16; ++r) {
    const int h = (sub << 5) + (r & 3) + ((r >> 2) << 3) + (hf << 2);
    op[h] = buf[r] * INV7;
  }
}

extern "C" void kernel_launch(void* const* d_in, const int* in_sizes, int n_in,
                              void* d_out, int out_size, void* d_ws, size_t ws_size,
                              hipStream_t stream) {
  (void)in_sizes; (void)n_in; (void)out_size; (void)ws_size;
  const float* pos   = (const float*)d_in[0];
  const float* gfeat = (const float*)d_in[1];
  const float* ffnA  = (const float*)d_in[2];
  const float* sigma = (const float*)d_in[3];
  const float* W0    = (const float*)d_in[4];
  const float* b0    = (const float*)d_in[5];
  const float* Wm    = (const float*)d_in[6];
  const float* bm    = (const float*)d_in[7];
  const float* Wh    = (const float*)d_in[8];
  const float* bh    = (const float*)d_in[9];
  float* out = (float*)d_out;
  unsigned char* ws = (unsigned char*)d_ws;

  hipLaunchKernelGGL(ffb_prep, dim3(448), dim3(256), 0, stream,
                     ffnA, sigma, Wm, bm, Wh, bh, ws);
  hipLaunchKernelGGL(ffb_main, dim3(4096), dim3(256), 0, stream,
                     pos, gfeat, W0, b0, ws, out);
}

// Round 4
// 266.165 us; speedup vs baseline: 1.3872x; 1.0613x over previous
//
#include <hip/hip_runtime.h>
#include <hip/hip_bf16.h>

// FFB encoder, MI355X. Round 11: whole-pass register prefetch of W.
// r10 diagnosis: W streams are L2-latency-bound (prefetch-1 = ~30cyc cover
// vs ~200-300cyc L2 latency -> ~85% stall duty in MFMA loops; MfmaUtil 24%,
// VALUBusy 37%, 45% neither). Fix: persistent frag arrays loaded one FULL
// pass ahead (~600-800cyc): mh/ml[8] (mid W, issued end of previous mid
// pass), hfr[8] (high W, issued top of mid pass, consumed next body).
// Epilogue constants staged to LDS once per WG (broadcast reads). Costs
// ~150 VGPR -> launch_bounds(256,3), 12 waves/CU; within-wave stalls gone
// so less TLP needed. Quad structure, X hi/lo in LDS, numerics identical.

typedef __bf16 bf16_t;
typedef __attribute__((ext_vector_type(8))) __bf16 bf16x8;
typedef __attribute__((ext_vector_type(4))) float f32x4;
typedef __attribute__((ext_vector_type(16))) float f32x16;

#define C56R 8.9126768f               // 56 / (2*pi)
#define INV7 0.14285714285714285f

// ws layout (bytes) — frag-linear, unchanged from r4-r10
#define OFF_WMF   0        // mid W hi  [7][4mt][8kc][64lane][8bf16]
#define OFF_WMFLO 229376   // mid W lo
#define OFF_WHF   458752   // high W hi
#define OFF_EPM   688128   // [7][2hf][4mt][16r] float4 {ap0, ap1, C56R*bm, C56R*bh}

union ChunkU { bf16x8 v; unsigned int d[4]; };

__device__ __forceinline__ unsigned short bfbits(float x) {
  bf16_t b = (bf16_t)x;
  return __builtin_bit_cast(unsigned short, b);
}
__device__ __forceinline__ float bf2f(unsigned short u) {
  return __builtin_bit_cast(float, (unsigned int)u << 16);
}
__device__ __forceinline__ void pack2(float v0, float v1,
                                      unsigned int& ph, unsigned int& pl) {
  unsigned short h0 = bfbits(v0), h1 = bfbits(v1);
  ph = (unsigned int)h0 | ((unsigned int)h1 << 16);
  float l0 = v0 - bf2f(h0), l1 = v1 - bf2f(h1);
  pl = (unsigned int)bfbits(l0) | ((unsigned int)bfbits(l1) << 16);
}

__global__ void ffb_prep(const float* __restrict__ ffnA, const float* __restrict__ sigma,
                         const float* __restrict__ Wm, const float* __restrict__ bm,
                         const float* __restrict__ Wh, const float* __restrict__ bh,
                         unsigned char* __restrict__ ws) {
  int i = blockIdx.x * 256 + threadIdx.x;  // 448*256 = 114688 exactly
  bf16_t* wmf = (bf16_t*)(ws + OFF_WMF);
  bf16_t* wml = (bf16_t*)(ws + OFF_WMFLO);
  bf16_t* whf = (bf16_t*)(ws + OFF_WHF);
  {
    // fragment reorder: [it][mt][kc][lane][j]
    int j    = i & 7;
    int lane = (i >> 3) & 63;
    int kc   = (i >> 9) & 7;
    int mt   = (i >> 12) & 3;
    int it   = i >> 14;                       // 0..6
    int ho   = (mt << 5) + (lane & 31);
    int hin  = (kc << 4) + ((lane >> 5) << 3) + j;
    int src  = (it << 14) + (ho << 7) + hin;
    float w  = Wm[src];
    bf16_t h = (bf16_t)w;
    wmf[i] = h;
    wml[i] = (bf16_t)(w - (float)h);
    whf[i] = (bf16_t)Wh[src];
  }
  if (i < 896) {
    int r  = i & 15;
    int mt = (i >> 4) & 3;
    int hf = (i >> 6) & 1;
    int it = i >> 7;                          // 0..6
    int h  = (mt << 5) + (r & 3) + ((r >> 2) << 3) + (hf << 2);
    float sg = sigma[it];
    f32x4 e;
    e.x = ffnA[it * 256 + h] * sg;
    e.y = ffnA[it * 256 + 128 + h] * sg;
    e.z = C56R * bm[it * 128 + h];
    e.w = C56R * bh[it * 128 + h];
    ((f32x4*)(ws + OFF_EPM))[i] = e;
  }
}

__launch_bounds__(256, 3)
__global__ void ffb_main(const float* __restrict__ pos,
                         const float* __restrict__ gfeat,
                         const float* __restrict__ W0,
                         const float* __restrict__ b0,
                         const unsigned char* __restrict__ ws,
                         float* __restrict__ out) {
  // LDS: [0,16K) X hi/lo for this quad; [16K, 30K) epilogue constants
  __shared__ __align__(16) unsigned char smem[30720];
  unsigned char* sX = smem;
  f32x4* sEPv = (f32x4*)(smem + 16384);
  float* sEPf = (float*)(smem + 16384);

  const int tid  = threadIdx.x;
  const int L    = tid & 63;
  const int sub  = tid >> 6;        // wave 0..3 = mt tile owned
  const int p    = L & 31;
  const int hf   = L >> 5;
  const int n    = (blockIdx.x << 5) + p;

  const bf16_t* __restrict__ WMH = (const bf16_t*)(ws + OFF_WMF);
  const bf16_t* __restrict__ WML = (const bf16_t*)(ws + OFF_WMFLO);
  const bf16_t* __restrict__ WHF = (const bf16_t*)(ws + OFF_WHF);
  const f32x4*  __restrict__ EPM = (const f32x4*)(ws + OFF_EPM);

  // ---- prefetch mid-W level 0 into registers (whole pass ahead)
  bf16x8 mh[8], ml[8], hfr[8];
  {
    const bf16_t* wh0 = WMH + (sub << 12) + (L << 3);
    const bf16_t* wl0 = WML + (sub << 12) + (L << 3);
    #pragma unroll
    for (int kc = 0; kc < 8; ++kc) {
      mh[kc] = *(const bf16x8*)(wh0 + (kc << 9));
      ml[kc] = *(const bf16x8*)(wl0 + (kc << 9));
    }
  }

  // ---- stage epilogue constants to LDS (896 float4, broadcast-read later)
  #pragma unroll
  for (int c = 0; c < 4; ++c) {
    int idx = tid + (c << 8);
    if (idx < 896) sEPv[idx] = EPM[idx];
  }

  const float p0 = pos[n * 3 + 0], p1 = pos[n * 3 + 1], p2 = pos[n * 3 + 2];
  if (sub == 0 && hf == 0) {
    out[(size_t)n * 131 + 0] = (p0 + 1.f) * 0.5f;
    out[(size_t)n * 131 + 1] = (p1 + 1.f) * 0.5f;
    out[(size_t)n * 131 + 2] = (p2 + 1.f) * 0.5f;
  }

  // ---- layer 0: each wave fills its 2 X chunks (B-frag layout) in LDS.
  #pragma unroll
  for (int cc = 0; cc < 2; ++cc) {
    const int c = (sub << 1) + cc;
    ChunkU chi, clo;
    #pragma unroll
    for (int jp = 0; jp < 4; ++jp) {
      int h0 = (c << 4) + (hf << 3) + 2 * jp;
      float d0 = __builtin_fmaf(p2, W0[h0*3+2], __builtin_fmaf(p1, W0[h0*3+1], p0 * W0[h0*3+0]));
      float d1 = __builtin_fmaf(p2, W0[h0*3+5], __builtin_fmaf(p1, W0[h0*3+4], p0 * W0[h0*3+3]));
      float v0 = __builtin_amdgcn_sinf(C56R * (d0 + b0[h0]));
      float v1 = __builtin_amdgcn_sinf(C56R * (d1 + b0[h0 + 1]));
      pack2(v0, v1, chi.d[jp], clo.d[jp]);
    }
    *(bf16x8*)(sX + (c << 10) + (L << 4))        = chi.v;
    *(bf16x8*)(sX + 8192 + (c << 10) + (L << 4)) = clo.v;
  }
  __syncthreads();   // X0 + epilogue constants visible

  f32x16 buf;
  #pragma unroll
  for (int r = 0; r < 16; ++r) buf[r] = 0.f;

  #pragma unroll 1
  for (int it = 0; it < 8; ++it) {
    // ---- high pass: level it-1, W frags already in hfr[] (prefetched
    //      during mid pass of previous body, ~600+ cyc ago)
    if (it > 0) {
      f32x16 acc;
      #pragma unroll
      for (int r = 0; r < 16; ++r) acc[r] = 0.f;
      #pragma unroll
      for (int kc = 0; kc < 8; ++kc) {
        bf16x8 xhc = *(const bf16x8*)(sX + (kc << 10) + (L << 4));
        acc = __builtin_amdgcn_mfma_f32_32x32x16_bf16(hfr[kc], xhc, acc, 0, 0, 0);
      }
      const int eb = ((((it - 1) << 1) + hf) << 2) + sub;
      #pragma unroll
      for (int r = 0; r < 16; ++r) {
        float cbh = sEPf[(eb * 16 + r) * 4 + 3];
        buf[r] += __builtin_amdgcn_sinf(__builtin_fmaf(acc[r], C56R, cbh));
      }
    }

    // ---- mid pass: level it, W frags already in mh/ml[] ----
    if (it < 7) {
      // prefetch high-W for level it (consumed in NEXT body's high pass)
      {
        const bf16_t* wb = WHF + (it << 14) + (sub << 12) + (L << 3);
        #pragma unroll
        for (int kc = 0; kc < 8; ++kc)
          hfr[kc] = *(const bf16x8*)(wb + (kc << 9));
      }

      f32x16 acc;
      #pragma unroll
      for (int r = 0; r < 16; ++r) acc[r] = 0.f;
      #pragma unroll
      for (int kc = 0; kc < 8; ++kc) {
        bf16x8 xhc = *(const bf16x8*)(sX + (kc << 10) + (L << 4));
        bf16x8 xlc = *(const bf16x8*)(sX + 8192 + (kc << 10) + (L << 4));
        acc = __builtin_amdgcn_mfma_f32_32x32x16_bf16(mh[kc], xhc, acc, 0, 0, 0);
        acc = __builtin_amdgcn_mfma_f32_32x32x16_bf16(ml[kc], xhc, acc, 0, 0, 0);
        acc = __builtin_amdgcn_mfma_f32_32x32x16_bf16(mh[kc], xlc, acc, 0, 0, 0);
      }

      // prefetch mid-W for level it+1 (consumed next body, ~800 cyc ahead)
      if (it < 6) {
        const bf16_t* wh = WMH + ((it + 1) << 14) + (sub << 12) + (L << 3);
        const bf16_t* wl = WML + ((it + 1) << 14) + (sub << 12) + (L << 3);
        #pragma unroll
        for (int kc = 0; kc < 8; ++kc) {
          mh[kc] = *(const bf16x8*)(wh + (kc << 9));
          ml[kc] = *(const bf16x8*)(wl + (kc << 9));
        }
      }

      __syncthreads();   // B1: all reads of X(it) complete

      // epilogue: x(it+1) = sin(grid) + sin(56*mid+b); write to B-layout LDS
      const float g0 = gfeat[n * 17 + 3 + 2 * it];
      const float g1 = gfeat[n * 17 + 4 + 2 * it];
      const int eb = (((it << 1) + hf) << 2) + sub;
      #pragma unroll
      for (int rp = 0; rp < 8; ++rp) {
        const int r = 2 * rp;
        f32x4 e0 = sEPv[eb * 16 + r];
        f32x4 e1 = sEPv[eb * 16 + r + 1];
        float sg0 = __builtin_amdgcn_sinf(__builtin_amdgcn_fractf(__builtin_fmaf(g1, e0.y, g0 * e0.x)));
        float sg1 = __builtin_amdgcn_sinf(__builtin_amdgcn_fractf(__builtin_fmaf(g1, e1.y, g0 * e1.x)));
        float sm0 = __builtin_amdgcn_sinf(__builtin_fmaf(acc[r],     C56R, e0.z));
        float sm1 = __builtin_amdgcn_sinf(__builtin_fmaf(acc[r + 1], C56R, e1.z));
        unsigned int phv, plv;
        pack2(sg0 + sm0, sg1 + sm1, phv, plv);
        const int h   = (sub << 5) + (r & 3) + ((r >> 2) << 3) + (hf << 2);
        const int off = ((h >> 4) << 10) + ((p + (((h >> 3) & 1) << 5)) << 4) + ((h & 7) << 1);
        *(unsigned int*)(sX + off)        = phv;
        *(unsigned int*)(sX + 8192 + off) = plv;
      }
      __syncthreads();   // B2: X(it+1) visible
    }
  }

  // ---- final store: this wave's mt=sub rows for its 32 points.
  float* op = out + (size_t)n * 131 + 3;
  #pragma unroll
  for (int r = 0; r < 16; ++r) {
    const int h = (sub << 5) + (r & 3) + ((r >> 2) << 3) + (hf << 2);
    op[h] = buf[r] * INV7;
  }
}

extern "C" void kernel_launch(void* const* d_in, const int* in_sizes, int n_in,
                              void* d_out, int out_size, void* d_ws, size_t ws_size,
                              hipStream_t stream) {
  (void)in_sizes; (void)n_in; (void)out_size; (void)ws_size;
  const float* pos   = (const float*)d_in[0];
  const float* gfeat = (const float*)d_in[1];
  const float* ffnA  = (const float*)d_in[2];
  const float* sigma = (const float*)d_in[3];
  const float* W0    = (const float*)d_in[4];
  const float* b0    = (const float*)d_in[5];
  const float* Wm    = (const float*)d_in[6];
  const float* bm    = (const float*)d_in[7];
  const float* Wh    = (const float*)d_in[8];
  const float* bh    = (const float*)d_in[9];
  float* out = (float*)d_out;
  unsigned char* ws = (unsigned char*)d_ws;

  hipLaunchKernelGGL(ffb_prep, dim3(448), dim3(256), 0, stream,
                     ffnA, sigma, Wm, bm, Wh, bh, ws);
  hipLaunchKernelGGL(ffb_main, dim3(4096), dim3(256), 0, stream,
                     pos, gfeat, W0, b0, ws, out);
}